// Round 9
// baseline (282.945 us; speedup 1.0000x reference)
//
#include <hip/hip_runtime.h>
#include <hip/hip_fp16.h>
#include <math.h>

#define N_NODES 50000
#define N_EDGES 1600000
#define NFEAT 256
#define NHID 128
#define NCLASS 40

#define BSHIFT 7
#define NBUCK 391            // ceil(50000 / 128)
#define CAP 5120             // per-bucket capacity (mean 4092)
#define EPB 4096             // edges per binA block -> 391 blocks

typedef _Float16 f16x8 __attribute__((ext_vector_type(8)));
typedef float f32x4 __attribute__((ext_vector_type(4)));

// ---------------- pass A: coarse binning by dst>>7 ----------------
__global__ __launch_bounds__(256) void k_binA(const int* __restrict__ src,
                                              const int* __restrict__ dst,
                                              int* __restrict__ gcur,
                                              unsigned int* __restrict__ packed) {
    __shared__ int lhist[NBUCK];
    __shared__ int lbase[NBUCK];
    __shared__ int lcur[NBUCK];
    int t = threadIdx.x;
    for (int i = t; i < NBUCK; i += 256) { lhist[i] = 0; lcur[i] = 0; }
    __syncthreads();
    int e0 = blockIdx.x * EPB;
    int e1 = min(e0 + EPB, N_EDGES);
    for (int e = e0 + t; e < e1; e += 256) {
        int b = dst[e] >> BSHIFT;
        atomicAdd(&lhist[b], 1);
    }
    __syncthreads();
    for (int i = t; i < NBUCK; i += 256)
        lbase[i] = atomicAdd(&gcur[i], lhist[i]);
    __syncthreads();
    for (int e = e0 + t; e < e1; e += 256) {
        int d = dst[e];
        int b = d >> BSHIFT;
        int r = atomicAdd(&lcur[b], 1);
        int pos = lbase[b] + r;
        if (pos < CAP)
            packed[(size_t)b * CAP + pos] =
                ((unsigned int)src[e] << BSHIFT) | (unsigned int)(d & 127);
    }
}

// ---------------- pass B: in-LDS fine sort per bucket + CSR metadata ----------------
__global__ __launch_bounds__(256) void k_binB(const int* __restrict__ gcur,
                                              const unsigned int* __restrict__ packed,
                                              unsigned short* __restrict__ esrc,
                                              int* __restrict__ row_beg,
                                              int* __restrict__ row_cnt,
                                              float* __restrict__ dinv) {
    __shared__ unsigned int sp[CAP];     // 20 KB
    __shared__ int hist[128];
    __shared__ int scan[128];
    __shared__ int cur[128];
    int b = blockIdx.x;
    int t = threadIdx.x;
    int cnt = min(gcur[b], CAP);
    if (t < 128) { hist[t] = 0; cur[t] = 0; }
    __syncthreads();
    const unsigned int* pin = packed + (size_t)b * CAP;
    for (int i = t; i < cnt; i += 256) {
        unsigned int w = pin[i];
        sp[i] = w;
        atomicAdd(&hist[w & 127], 1);
    }
    __syncthreads();
    if (t == 0) {
        int s = 0;
        for (int i = 0; i < 128; i++) { scan[i] = s; s += hist[i]; }
    }
    __syncthreads();
    for (int i = t; i < cnt; i += 256) {
        unsigned int w = sp[i];
        int dl = (int)(w & 127u);
        int r = atomicAdd(&cur[dl], 1);
        esrc[(size_t)b * CAP + scan[dl] + r] = (unsigned short)(w >> BSHIFT);
    }
    if (t < 128) {
        int node = b * 128 + t;
        if (node < N_NODES) {
            row_beg[node] = b * CAP + scan[t];
            row_cnt[node] = hist[t];
            dinv[node] = rsqrtf((float)(hist[t] + 1));
        }
    }
}

// ---------------- prep: W transposes to fp16 + gcur zeroing ----------------
__global__ __launch_bounds__(256) void k_prep(const float* __restrict__ W1,
                                              const float* __restrict__ W2,
                                              __half* __restrict__ w1t,
                                              __half* __restrict__ w2t,
                                              int* __restrict__ gcur) {
    int t = blockIdx.x * 256 + threadIdx.x;
    if (t < NBUCK) gcur[t] = 0;
    if (t < 128 * 256) {
        int n = t >> 8, k = t & 255;
        w1t[t] = __float2half(W1[k * NHID + n]);
    }
    if (t < 48 * 128) {
        int n = t >> 7, k = t & 127;
        w2t[t] = __float2half(n < NCLASS ? W2[k * NCLASS + n] : 0.0f);
    }
}

// ---------------- GEMM1 (MFMA): h1h(fp16) = x @ W1 ----------------
#define G1_LDA 72
#define G1_LDB 72
#define G1_LDE 136
__global__ __launch_bounds__(256) void k_gemm1(const float* __restrict__ x,
                                               const __half* __restrict__ w1t,
                                               __half* __restrict__ h1h) {
    __shared__ __half smem[64 * G1_LDA + 128 * G1_LDB];   // 27.6 KB
    __half* sA = smem;
    __half* sB = smem + 64 * G1_LDA;
    int t = threadIdx.x;
    int rbase = blockIdx.x * 64;
    int lane = t & 63, wv = t >> 6;
    int m = lane & 15, quad = lane >> 4;
    f32x4 acc[8];
    #pragma unroll
    for (int i = 0; i < 8; i++) acc[i] = (f32x4)0.0f;

    int arow = t >> 2, aseg = t & 3;
    int grow = rbase + arow;
    bool avalid = grow < N_NODES;
    int bn = t >> 1, bseg = t & 1;

    for (int k0 = 0; k0 < NFEAT; k0 += 64) {
        const float4* gs = (const float4*)(x + (size_t)grow * NFEAT + k0 + aseg * 16);
        __half* ad = sA + arow * G1_LDA + aseg * 16;
        #pragma unroll
        for (int i = 0; i < 4; i++) {
            float4 v = avalid ? gs[i] : make_float4(0.f, 0.f, 0.f, 0.f);
            __half2 h0 = __float22half2_rn(make_float2(v.x, v.y));
            __half2 h1 = __float22half2_rn(make_float2(v.z, v.w));
            uint2 st;
            st.x = __builtin_bit_cast(unsigned int, h0);
            st.y = __builtin_bit_cast(unsigned int, h1);
            *(uint2*)(ad + i * 4) = st;
        }
        const uint4* ws4 = (const uint4*)(w1t + bn * NFEAT + k0 + bseg * 32);
        uint4* bd = (uint4*)(sB + bn * G1_LDB + bseg * 32);
        #pragma unroll
        for (int i = 0; i < 4; i++) bd[i] = ws4[i];
        __syncthreads();
        #pragma unroll
        for (int kk = 0; kk < 64; kk += 32) {
            f16x8 af = *(const f16x8*)(sA + (wv * 16 + m) * G1_LDA + kk + quad * 8);
            #pragma unroll
            for (int t8 = 0; t8 < 8; t8++) {
                f16x8 bf = *(const f16x8*)(sB + (t8 * 16 + m) * G1_LDB + kk + quad * 8);
                acc[t8] = __builtin_amdgcn_mfma_f32_16x16x32_f16(af, bf, acc[t8], 0, 0, 0);
            }
        }
        __syncthreads();
    }
    __half* eb = smem;
    #pragma unroll
    for (int t8 = 0; t8 < 8; t8++) {
        #pragma unroll
        for (int r = 0; r < 4; r++)
            eb[(wv * 16 + quad * 4 + r) * G1_LDE + t8 * 16 + m] = __float2half(acc[t8][r]);
    }
    __syncthreads();
    if (avalid) {
        const uint4* es = (const uint4*)(eb + arow * G1_LDE + aseg * 32);
        uint4* od = (uint4*)(h1h + (size_t)grow * NHID + aseg * 32);
        #pragma unroll
        for (int i = 0; i < 4; i++) od[i] = es[i];
    }
}

// ---------------- GEMM2 (MFMA): h2p(fp16, row stride 40) = h1p @ W2 ------------
#define G2_LDA 136
#define G2_LDB 136
#define G2_LDE 40
__global__ __launch_bounds__(256) void k_gemm2(const __half* __restrict__ h1p,
                                               const __half* __restrict__ w2t,
                                               __half* __restrict__ h2p) {
    __shared__ __half smem[64 * G2_LDA + 48 * G2_LDB];  // 30.5 KB
    __half* sA = smem;
    __half* sB = smem + 64 * G2_LDA;
    int t = threadIdx.x;
    int rbase = blockIdx.x * 64;
    int lane = t & 63, wv = t >> 6;
    int m = lane & 15, quad = lane >> 4;
    f32x4 acc[3];
    #pragma unroll
    for (int i = 0; i < 3; i++) acc[i] = (f32x4)0.0f;

    int arow = t >> 2, aseg = t & 3;
    int grow = rbase + arow;
    bool avalid = grow < N_NODES;

    #pragma unroll
    for (int i = 0; i < 3; i++) {
        int idx = t + i * 256;
        int n = idx >> 4, seg = idx & 15;
        *(uint4*)(sB + n * G2_LDB + seg * 8) = *(const uint4*)(w2t + n * NHID + seg * 8);
    }
    {
        const uint4* gs = (const uint4*)(h1p + (size_t)grow * NHID + aseg * 32);
        uint4* ad = (uint4*)(sA + arow * G2_LDA + aseg * 32);
        uint4 z; z.x = z.y = z.z = z.w = 0;
        #pragma unroll
        for (int i = 0; i < 4; i++) ad[i] = avalid ? gs[i] : z;
    }
    __syncthreads();
    #pragma unroll
    for (int kk = 0; kk < 128; kk += 32) {
        f16x8 af = *(const f16x8*)(sA + (wv * 16 + m) * G2_LDA + kk + quad * 8);
        #pragma unroll
        for (int t3 = 0; t3 < 3; t3++) {
            f16x8 bf = *(const f16x8*)(sB + (t3 * 16 + m) * G2_LDB + kk + quad * 8);
            acc[t3] = __builtin_amdgcn_mfma_f32_16x16x32_f16(af, bf, acc[t3], 0, 0, 0);
        }
    }
    __syncthreads();
    // epilogue: 64 x 40 halves
    __half* eb = smem;
    #pragma unroll
    for (int t3 = 0; t3 < 3; t3++) {
        int col = t3 * 16 + m;
        if (col < NCLASS) {
            #pragma unroll
            for (int r = 0; r < 4; r++)
                eb[(wv * 16 + quad * 4 + r) * G2_LDE + col] = __float2half(acc[t3][r]);
        }
    }
    __syncthreads();
    // store 64 rows x 5 uint4 = 320 uint4 (grid-stride over 256 threads)
    for (int idx = t; idx < 320; idx += 256) {
        int row = idx / 5, seg = idx % 5;
        int gr = rbase + row;
        if (gr < N_NODES)
            *(uint4*)(h2p + (size_t)gr * G2_LDE + seg * 8) =
                *(const uint4*)(eb + row * G2_LDE + seg * 8);
    }
}

__device__ __forceinline__ void acc8f(float* acc, uint4 v, float d) {
    float2 a0 = __half22float2(__builtin_bit_cast(__half2, v.x));
    float2 a1 = __half22float2(__builtin_bit_cast(__half2, v.y));
    float2 a2 = __half22float2(__builtin_bit_cast(__half2, v.z));
    float2 a3 = __half22float2(__builtin_bit_cast(__half2, v.w));
    acc[0] = fmaf(a0.x, d, acc[0]); acc[1] = fmaf(a0.y, d, acc[1]);
    acc[2] = fmaf(a1.x, d, acc[2]); acc[3] = fmaf(a1.y, d, acc[3]);
    acc[4] = fmaf(a2.x, d, acc[4]); acc[5] = fmaf(a2.y, d, acc[5]);
    acc[6] = fmaf(a3.x, d, acc[6]); acc[7] = fmaf(a3.y, d, acc[7]);
}

// ---------------- agg1: split-wave, fp16 accum, 8-deep gathers ----------------
__global__ __launch_bounds__(64) void k_agg1(const __half* __restrict__ h1h,
                                             const float* __restrict__ dinv,
                                             const int* __restrict__ row_beg,
                                             const int* __restrict__ row_cnt,
                                             const unsigned short* __restrict__ esrc,
                                             const float* __restrict__ b1,
                                             const float* __restrict__ mask,
                                             __half* __restrict__ h1p) {
    int i = blockIdx.x;
    int lane = threadIdx.x;
    int q = lane >> 4;
    int fl = lane & 15;
    const uint4* hv4 = (const uint4*)h1h;
    float di = dinv[i];
    __half2 hacc[4];
    __half2 hz = __half2half2(__float2half(0.0f));
    hacc[0] = hz; hacc[1] = hz; hacc[2] = hz; hacc[3] = hz;
    int s0 = row_beg[i], cnt = row_cnt[i];
    for (int base = 0; base < cnt; base += 64) {
        int idx = base + lane;
        int sv = (idx < cnt) ? (int)esrc[s0 + idx] : 0;
        float dv = (idx < cnt) ? dinv[sv] : 0.0f;
        int n = min(64, cnt - base);
        int nr = (n + 31) & ~31;
        for (int j = 0; j < nr; j += 32) {
            int ss[8]; __half2 dd[8]; uint4 vv[8];
            #pragma unroll
            for (int k = 0; k < 8; k++) {
                int jx = j + 4 * k + q;
                ss[k] = __shfl(sv, jx);
                float df = __shfl(dv, jx);
                dd[k] = __half2half2(__float2half(df));
            }
            #pragma unroll
            for (int k = 0; k < 8; k++) vv[k] = hv4[(size_t)ss[k] * 16 + fl];
            #pragma unroll
            for (int k = 0; k < 8; k++) {
                hacc[0] = __hfma2(__builtin_bit_cast(__half2, vv[k].x), dd[k], hacc[0]);
                hacc[1] = __hfma2(__builtin_bit_cast(__half2, vv[k].y), dd[k], hacc[1]);
                hacc[2] = __hfma2(__builtin_bit_cast(__half2, vv[k].z), dd[k], hacc[2]);
                hacc[3] = __hfma2(__builtin_bit_cast(__half2, vv[k].w), dd[k], hacc[3]);
            }
        }
    }
    float acc[8];
    #pragma unroll
    for (int k2 = 0; k2 < 4; k2++) {
        float2 f = __half22float2(hacc[k2]);
        acc[2 * k2] = f.x; acc[2 * k2 + 1] = f.y;
    }
    #pragma unroll
    for (int k = 0; k < 8; k++) {
        acc[k] += __shfl_xor(acc[k], 16);
        acc[k] += __shfl_xor(acc[k], 32);
    }
    if (q == 0) {
        uint4 sv4 = hv4[(size_t)i * 16 + fl];
        acc8f(acc, sv4, di);
        float4 bb0 = ((const float4*)b1)[fl * 2];
        float4 bb1 = ((const float4*)b1)[fl * 2 + 1];
        const float4* mrow = (const float4*)(mask + (size_t)i * NHID);
        float4 mm0 = mrow[fl * 2];
        float4 mm1 = mrow[fl * 2 + 1];
        float o0 = fmaxf(fmaf(acc[0], di, bb0.x), 0.f) * mm0.x;
        float o1 = fmaxf(fmaf(acc[1], di, bb0.y), 0.f) * mm0.y;
        float o2 = fmaxf(fmaf(acc[2], di, bb0.z), 0.f) * mm0.z;
        float o3 = fmaxf(fmaf(acc[3], di, bb0.w), 0.f) * mm0.w;
        float o4 = fmaxf(fmaf(acc[4], di, bb1.x), 0.f) * mm1.x;
        float o5 = fmaxf(fmaf(acc[5], di, bb1.y), 0.f) * mm1.y;
        float o6 = fmaxf(fmaf(acc[6], di, bb1.z), 0.f) * mm1.z;
        float o7 = fmaxf(fmaf(acc[7], di, bb1.w), 0.f) * mm1.w;
        __half2 p0 = __float22half2_rn(make_float2(o0, o1));
        __half2 p1 = __float22half2_rn(make_float2(o2, o3));
        __half2 p2 = __float22half2_rn(make_float2(o4, o5));
        __half2 p3 = __float22half2_rn(make_float2(o6, o7));
        uint4 st;
        st.x = __builtin_bit_cast(unsigned int, p0);
        st.y = __builtin_bit_cast(unsigned int, p1);
        st.z = __builtin_bit_cast(unsigned int, p2);
        st.w = __builtin_bit_cast(unsigned int, p3);
        ((uint4*)h1p)[(size_t)i * 16 + fl] = st;
    }
}

// ---------------- agg2 + bias + log_softmax (stride-40 rows, fp16 accum) -------
__global__ __launch_bounds__(64) void k_agg2(const __half* __restrict__ h2p,
                                             const float* __restrict__ dinv,
                                             const int* __restrict__ row_beg,
                                             const int* __restrict__ row_cnt,
                                             const unsigned short* __restrict__ esrc,
                                             const float* __restrict__ b2,
                                             float* __restrict__ out) {
    int i = blockIdx.x;
    int lane = threadIdx.x;
    int o8 = lane >> 3;
    int fl = lane & 7;
    bool gact = fl < 5;                      // 5 uint4 per row (40 halves)
    const uint4* hv4 = (const uint4*)h2p;
    float di = dinv[i];
    __half2 hacc[4];
    __half2 hz = __half2half2(__float2half(0.0f));
    hacc[0] = hz; hacc[1] = hz; hacc[2] = hz; hacc[3] = hz;
    int s0 = row_beg[i], cnt = row_cnt[i];
    uint4 zero4; zero4.x = zero4.y = zero4.z = zero4.w = 0;
    for (int base = 0; base < cnt; base += 64) {
        int idx = base + lane;
        int sv = (idx < cnt) ? (int)esrc[s0 + idx] : 0;
        float dv = (idx < cnt) ? dinv[sv] : 0.0f;
        int n = min(64, cnt - base);
        int nr = (n + 31) & ~31;
        for (int j = 0; j < nr; j += 32) {
            int ss[4]; __half2 dd[4]; uint4 vv[4];
            #pragma unroll
            for (int k = 0; k < 4; k++) {
                int jx = j + 8 * k + o8;
                ss[k] = __shfl(sv, jx);
                float df = __shfl(dv, jx);
                dd[k] = __half2half2(__float2half(df));
            }
            #pragma unroll
            for (int k = 0; k < 4; k++) vv[k] = gact ? hv4[(size_t)ss[k] * 5 + fl] : zero4;
            #pragma unroll
            for (int k = 0; k < 4; k++) {
                hacc[0] = __hfma2(__builtin_bit_cast(__half2, vv[k].x), dd[k], hacc[0]);
                hacc[1] = __hfma2(__builtin_bit_cast(__half2, vv[k].y), dd[k], hacc[1]);
                hacc[2] = __hfma2(__builtin_bit_cast(__half2, vv[k].z), dd[k], hacc[2]);
                hacc[3] = __hfma2(__builtin_bit_cast(__half2, vv[k].w), dd[k], hacc[3]);
            }
        }
    }
    float acc[8];
    #pragma unroll
    for (int k2 = 0; k2 < 4; k2++) {
        float2 f = __half22float2(hacc[k2]);
        acc[2 * k2] = f.x; acc[2 * k2 + 1] = f.y;
    }
    if (o8 == 0 && gact) {
        uint4 sv4 = hv4[(size_t)i * 5 + fl];
        acc8f(acc, sv4, di);
    }
    #pragma unroll
    for (int k = 0; k < 8; k++) {
        acc[k] += __shfl_xor(acc[k], 8);
        acc[k] += __shfl_xor(acc[k], 16);
        acc[k] += __shfl_xor(acc[k], 32);
    }
    if (o8 == 0) {
        bool act = (fl < 5);
        float val[8];
        float m = -INFINITY;
        if (act) {
            float4 bb0 = ((const float4*)b2)[fl * 2];
            float4 bb1 = ((const float4*)b2)[fl * 2 + 1];
            val[0] = fmaf(acc[0], di, bb0.x);
            val[1] = fmaf(acc[1], di, bb0.y);
            val[2] = fmaf(acc[2], di, bb0.z);
            val[3] = fmaf(acc[3], di, bb0.w);
            val[4] = fmaf(acc[4], di, bb1.x);
            val[5] = fmaf(acc[5], di, bb1.y);
            val[6] = fmaf(acc[6], di, bb1.z);
            val[7] = fmaf(acc[7], di, bb1.w);
            #pragma unroll
            for (int k = 0; k < 8; k++) m = fmaxf(m, val[k]);
        }
        m = fmaxf(m, __shfl_xor(m, 1));
        m = fmaxf(m, __shfl_xor(m, 2));
        m = fmaxf(m, __shfl_xor(m, 4));
        float ss = 0.f;
        if (act) {
            #pragma unroll
            for (int k = 0; k < 8; k++) ss += expf(val[k] - m);
        }
        ss += __shfl_xor(ss, 1);
        ss += __shfl_xor(ss, 2);
        ss += __shfl_xor(ss, 4);
        if (act) {
            float ls = m + logf(ss);
            float4 r0 = make_float4(val[0] - ls, val[1] - ls, val[2] - ls, val[3] - ls);
            float4 r1 = make_float4(val[4] - ls, val[5] - ls, val[6] - ls, val[7] - ls);
            float4* orow = (float4*)(out + (size_t)i * NCLASS + fl * 8);
            orow[0] = r0;
            orow[1] = r1;
        }
    }
}

extern "C" void kernel_launch(void* const* d_in, const int* in_sizes, int n_in,
                              void* d_out, int out_size, void* d_ws, size_t ws_size,
                              hipStream_t stream) {
    const float* x    = (const float*)d_in[0];
    const int*   ei   = (const int*)d_in[1];
    const float* W1   = (const float*)d_in[2];
    const float* b1   = (const float*)d_in[3];
    const float* W2   = (const float*)d_in[4];
    const float* b2   = (const float*)d_in[5];
    const float* mask = (const float*)d_in[6];
    float* out = (float*)d_out;

    const int* src = ei;
    const int* dst = ei + N_EDGES;

    char* ws = (char*)d_ws;
    size_t off = 0;
    __half* h1p    = (__half*)(ws + off); off += (size_t)N_NODES * NHID * 2;   // 12.8 MB
    __half* h1h    = (__half*)(ws + off); off += (size_t)N_NODES * NHID * 2;   // 12.8 MB
    unsigned short* esrc = (unsigned short*)(ws + off);
    off += ((size_t)NBUCK * CAP * 2 + 255) & ~(size_t)255;                     // 4.0 MB
    float*  dinv   = (float*) (ws + off); off += 200192;
    int*   row_beg = (int*)   (ws + off); off += 200192;
    int*   row_cnt = (int*)   (ws + off); off += 200192;
    int*   gcur    = (int*)   (ws + off); off += 4096;
    __half* w1t    = (__half*)(ws + off); off += 128 * 256 * 2;                // 64 KB
    __half* w2t    = (__half*)(ws + off); off += 48 * 128 * 2;                 // 12 KB

    unsigned int* packed = (unsigned int*)h1p;  // binA/binB lifetime only (8 MB)
    __half* h2p = h1h;                           // gemm2/agg2 lifetime only (4 MB)

    k_prep<<<128, 256, 0, stream>>>(W1, W2, w1t, w2t, gcur);
    k_binA<<<(N_EDGES + EPB - 1) / EPB, 256, 0, stream>>>(src, dst, gcur, packed);
    k_binB<<<NBUCK, 256, 0, stream>>>(gcur, packed, esrc, row_beg, row_cnt, dinv);

    k_gemm1<<<(N_NODES + 63) / 64, 256, 0, stream>>>(x, w1t, h1h);
    k_agg1<<<N_NODES, 64, 0, stream>>>(h1h, dinv, row_beg, row_cnt, esrc, b1, mask, h1p);
    k_gemm2<<<(N_NODES + 63) / 64, 256, 0, stream>>>(h1p, w2t, h2p);
    k_agg2<<<N_NODES, 64, 0, stream>>>(h2p, dinv, row_beg, row_cnt, esrc, b2, out);
}

// Round 10
// 278.649 us; speedup vs baseline: 1.0154x; 1.0154x over previous
//
#include <hip/hip_runtime.h>
#include <hip/hip_fp16.h>
#include <math.h>

#define N_NODES 50000
#define N_EDGES 1600000
#define NFEAT 256
#define NHID 128
#define NCLASS 40

#define BSHIFT 7
#define NBUCK 391            // ceil(50000 / 128)
#define CAP 5120             // per-bucket capacity (mean 4092)
#define EPB 4096             // edges per binA block -> 391 blocks
#define SEGN 4
#define SEGSZ 12800          // src segment size: 12800 rows * 256B = 3.2MB of h1h

typedef _Float16 f16x8 __attribute__((ext_vector_type(8)));
typedef float f32x4 __attribute__((ext_vector_type(4)));

// ---------------- pass A: coarse binning by dst>>7 ----------------
__global__ __launch_bounds__(256) void k_binA(const int* __restrict__ src,
                                              const int* __restrict__ dst,
                                              int* __restrict__ gcur,
                                              unsigned int* __restrict__ packed) {
    __shared__ int lhist[NBUCK];
    __shared__ int lbase[NBUCK];
    __shared__ int lcur[NBUCK];
    int t = threadIdx.x;
    for (int i = t; i < NBUCK; i += 256) { lhist[i] = 0; lcur[i] = 0; }
    __syncthreads();
    int e0 = blockIdx.x * EPB;
    int e1 = min(e0 + EPB, N_EDGES);
    for (int e = e0 + t; e < e1; e += 256) {
        int b = dst[e] >> BSHIFT;
        atomicAdd(&lhist[b], 1);
    }
    __syncthreads();
    for (int i = t; i < NBUCK; i += 256)
        lbase[i] = atomicAdd(&gcur[i], lhist[i]);
    __syncthreads();
    for (int e = e0 + t; e < e1; e += 256) {
        int d = dst[e];
        int b = d >> BSHIFT;
        int r = atomicAdd(&lcur[b], 1);
        int pos = lbase[b] + r;
        if (pos < CAP)
            packed[(size_t)b * CAP + pos] =
                ((unsigned int)src[e] << BSHIFT) | (unsigned int)(d & 127);
    }
}

// ---------------- pass B: dual in-LDS sorts per bucket ----------------
// esrc_seg: key = seg*128 + dstlow  (segment-major, for phased agg1)
// esrc_row: key = dstlow            (row-contiguous, for agg2)
__global__ __launch_bounds__(256) void k_binB(const int* __restrict__ gcur,
                                              const unsigned int* __restrict__ packed,
                                              unsigned short* __restrict__ esrc_seg,
                                              unsigned short* __restrict__ esrc_row,
                                              int* __restrict__ sbeg,
                                              int* __restrict__ scnt,
                                              int* __restrict__ row_beg,
                                              int* __restrict__ row_cnt,
                                              float* __restrict__ dinv) {
    __shared__ unsigned int sp[CAP];     // 20 KB
    __shared__ int hist[512];
    __shared__ int scan[512];
    __shared__ int cur[512];
    __shared__ int psum[64];
    int b = blockIdx.x;
    int t = threadIdx.x;
    int cnt = min(gcur[b], CAP);
    for (int i = t; i < 512; i += 256) { hist[i] = 0; cur[i] = 0; }
    __syncthreads();
    const unsigned int* pin = packed + (size_t)b * CAP;
    for (int i = t; i < cnt; i += 256) {
        unsigned int w = pin[i];
        sp[i] = w;
        int srcv = (int)(w >> BSHIFT);
        atomicAdd(&hist[(srcv / SEGSZ) * 128 + (int)(w & 127u)], 1);
    }
    __syncthreads();
    // two-level exclusive scan over 512
    if (t < 64) {
        int s = 0;
        #pragma unroll
        for (int j = 0; j < 8; j++) s += hist[t * 8 + j];
        psum[t] = s;
    }
    __syncthreads();
    if (t == 0) {
        int s = 0;
        for (int j = 0; j < 64; j++) { int v = psum[j]; psum[j] = s; s += v; }
    }
    __syncthreads();
    if (t < 64) {
        int s = psum[t];
        #pragma unroll
        for (int j = 0; j < 8; j++) { scan[t * 8 + j] = s; s += hist[t * 8 + j]; }
    }
    __syncthreads();
    for (int i = t; i < cnt; i += 256) {
        unsigned int w = sp[i];
        int srcv = (int)(w >> BSHIFT);
        int key = (srcv / SEGSZ) * 128 + (int)(w & 127u);
        int r = atomicAdd(&cur[key], 1);
        esrc_seg[(size_t)b * CAP + scan[key] + r] = (unsigned short)srcv;
    }
    if (t < 128) {
        int node = b * 128 + t;
        if (node < N_NODES) {
            int tot = 0;
            #pragma unroll
            for (int s = 0; s < SEGN; s++) {
                sbeg[node * 4 + s] = b * CAP + scan[s * 128 + t];
                scnt[node * 4 + s] = hist[s * 128 + t];
                tot += hist[s * 128 + t];
            }
            row_cnt[node] = tot;
            dinv[node] = rsqrtf((float)(tot + 1));
        }
    }
    // ---- pass 2: row-major order ----
    __syncthreads();
    if (t < 128) { hist[t] = 0; cur[t] = 0; }
    __syncthreads();
    for (int i = t; i < cnt; i += 256) atomicAdd(&hist[sp[i] & 127u], 1);
    __syncthreads();
    if (t == 0) {
        int s = 0;
        for (int j = 0; j < 128; j++) { int v = hist[j]; scan[j] = s; s += v; }
    }
    __syncthreads();
    for (int i = t; i < cnt; i += 256) {
        unsigned int w = sp[i];
        int dl = (int)(w & 127u);
        int r = atomicAdd(&cur[dl], 1);
        esrc_row[(size_t)b * CAP + scan[dl] + r] = (unsigned short)(w >> BSHIFT);
    }
    if (t < 128) {
        int node = b * 128 + t;
        if (node < N_NODES) row_beg[node] = b * CAP + scan[t];
    }
}

// ---------------- prep: W transposes to fp16 + gcur zeroing ----------------
__global__ __launch_bounds__(256) void k_prep(const float* __restrict__ W1,
                                              const float* __restrict__ W2,
                                              __half* __restrict__ w1t,
                                              __half* __restrict__ w2t,
                                              int* __restrict__ gcur) {
    int t = blockIdx.x * 256 + threadIdx.x;
    if (t < NBUCK) gcur[t] = 0;
    if (t < 128 * 256) {
        int n = t >> 8, k = t & 255;
        w1t[t] = __float2half(W1[k * NHID + n]);
    }
    if (t < 48 * 128) {
        int n = t >> 7, k = t & 127;
        w2t[t] = __float2half(n < NCLASS ? W2[k * NCLASS + n] : 0.0f);
    }
}

// ---------------- GEMM1 (MFMA): h1h(fp16) = x @ W1 ----------------
#define G1_LDA 72
#define G1_LDB 72
#define G1_LDE 136
__global__ __launch_bounds__(256) void k_gemm1(const float* __restrict__ x,
                                               const __half* __restrict__ w1t,
                                               __half* __restrict__ h1h) {
    __shared__ __half smem[64 * G1_LDA + 128 * G1_LDB];   // 27.6 KB
    __half* sA = smem;
    __half* sB = smem + 64 * G1_LDA;
    int t = threadIdx.x;
    int rbase = blockIdx.x * 64;
    int lane = t & 63, wv = t >> 6;
    int m = lane & 15, quad = lane >> 4;
    f32x4 acc[8];
    #pragma unroll
    for (int i = 0; i < 8; i++) acc[i] = (f32x4)0.0f;

    int arow = t >> 2, aseg = t & 3;
    int grow = rbase + arow;
    bool avalid = grow < N_NODES;
    int bn = t >> 1, bseg = t & 1;

    for (int k0 = 0; k0 < NFEAT; k0 += 64) {
        const float4* gs = (const float4*)(x + (size_t)grow * NFEAT + k0 + aseg * 16);
        __half* ad = sA + arow * G1_LDA + aseg * 16;
        #pragma unroll
        for (int i = 0; i < 4; i++) {
            float4 v = avalid ? gs[i] : make_float4(0.f, 0.f, 0.f, 0.f);
            __half2 h0 = __float22half2_rn(make_float2(v.x, v.y));
            __half2 h1 = __float22half2_rn(make_float2(v.z, v.w));
            uint2 st;
            st.x = __builtin_bit_cast(unsigned int, h0);
            st.y = __builtin_bit_cast(unsigned int, h1);
            *(uint2*)(ad + i * 4) = st;
        }
        const uint4* ws4 = (const uint4*)(w1t + bn * NFEAT + k0 + bseg * 32);
        uint4* bd = (uint4*)(sB + bn * G1_LDB + bseg * 32);
        #pragma unroll
        for (int i = 0; i < 4; i++) bd[i] = ws4[i];
        __syncthreads();
        #pragma unroll
        for (int kk = 0; kk < 64; kk += 32) {
            f16x8 af = *(const f16x8*)(sA + (wv * 16 + m) * G1_LDA + kk + quad * 8);
            #pragma unroll
            for (int t8 = 0; t8 < 8; t8++) {
                f16x8 bf = *(const f16x8*)(sB + (t8 * 16 + m) * G1_LDB + kk + quad * 8);
                acc[t8] = __builtin_amdgcn_mfma_f32_16x16x32_f16(af, bf, acc[t8], 0, 0, 0);
            }
        }
        __syncthreads();
    }
    __half* eb = smem;
    #pragma unroll
    for (int t8 = 0; t8 < 8; t8++) {
        #pragma unroll
        for (int r = 0; r < 4; r++)
            eb[(wv * 16 + quad * 4 + r) * G1_LDE + t8 * 16 + m] = __float2half(acc[t8][r]);
    }
    __syncthreads();
    if (avalid) {
        const uint4* es = (const uint4*)(eb + arow * G1_LDE + aseg * 32);
        uint4* od = (uint4*)(h1h + (size_t)grow * NHID + aseg * 32);
        #pragma unroll
        for (int i = 0; i < 4; i++) od[i] = es[i];
    }
}

// ---------------- GEMM2 (MFMA): h2p(fp16, stride 64) = h1p @ W2 ----------------
#define G2_LDA 136
#define G2_LDB 136
#define G2_LDE 72
__global__ __launch_bounds__(256) void k_gemm2(const __half* __restrict__ h1p,
                                               const __half* __restrict__ w2t,
                                               __half* __restrict__ h2p) {
    __shared__ __half smem[64 * G2_LDA + 48 * G2_LDB];  // 30.5 KB
    __half* sA = smem;
    __half* sB = smem + 64 * G2_LDA;
    int t = threadIdx.x;
    int rbase = blockIdx.x * 64;
    int lane = t & 63, wv = t >> 6;
    int m = lane & 15, quad = lane >> 4;
    f32x4 acc[3];
    #pragma unroll
    for (int i = 0; i < 3; i++) acc[i] = (f32x4)0.0f;

    int arow = t >> 2, aseg = t & 3;
    int grow = rbase + arow;
    bool avalid = grow < N_NODES;

    #pragma unroll
    for (int i = 0; i < 3; i++) {
        int idx = t + i * 256;
        int n = idx >> 4, seg = idx & 15;
        *(uint4*)(sB + n * G2_LDB + seg * 8) = *(const uint4*)(w2t + n * NHID + seg * 8);
    }
    {
        const uint4* gs = (const uint4*)(h1p + (size_t)grow * NHID + aseg * 32);
        uint4* ad = (uint4*)(sA + arow * G2_LDA + aseg * 32);
        uint4 z; z.x = z.y = z.z = z.w = 0;
        #pragma unroll
        for (int i = 0; i < 4; i++) ad[i] = avalid ? gs[i] : z;
    }
    __syncthreads();
    #pragma unroll
    for (int kk = 0; kk < 128; kk += 32) {
        f16x8 af = *(const f16x8*)(sA + (wv * 16 + m) * G2_LDA + kk + quad * 8);
        #pragma unroll
        for (int t3 = 0; t3 < 3; t3++) {
            f16x8 bf = *(const f16x8*)(sB + (t3 * 16 + m) * G2_LDB + kk + quad * 8);
            acc[t3] = __builtin_amdgcn_mfma_f32_16x16x32_f16(af, bf, acc[t3], 0, 0, 0);
        }
    }
    __syncthreads();
    // epilogue: 64 x 64 halves (cols 48..63 zero)
    __half* eb = smem;
    #pragma unroll
    for (int t3 = 0; t3 < 3; t3++) {
        #pragma unroll
        for (int r = 0; r < 4; r++)
            eb[(wv * 16 + quad * 4 + r) * G2_LDE + t3 * 16 + m] = __float2half(acc[t3][r]);
    }
    {
        int zr = t >> 2, zc = 48 + (t & 3) * 4;
        uint2 z; z.x = z.y = 0;
        *(uint2*)(eb + zr * G2_LDE + zc) = z;
    }
    __syncthreads();
    #pragma unroll
    for (int i = 0; i < 2; i++) {
        int idx = t + i * 256;
        int row = idx >> 3, seg = idx & 7;
        int gr = rbase + row;
        if (gr < N_NODES)
            *(uint4*)(h2p + (size_t)gr * 64 + seg * 8) = *(const uint4*)(eb + row * G2_LDE + seg * 8);
    }
}

__device__ __forceinline__ void acc8f(float* acc, uint4 v, float d) {
    float2 a0 = __half22float2(__builtin_bit_cast(__half2, v.x));
    float2 a1 = __half22float2(__builtin_bit_cast(__half2, v.y));
    float2 a2 = __half22float2(__builtin_bit_cast(__half2, v.z));
    float2 a3 = __half22float2(__builtin_bit_cast(__half2, v.w));
    acc[0] = fmaf(a0.x, d, acc[0]); acc[1] = fmaf(a0.y, d, acc[1]);
    acc[2] = fmaf(a1.x, d, acc[2]); acc[3] = fmaf(a1.y, d, acc[3]);
    acc[4] = fmaf(a2.x, d, acc[4]); acc[5] = fmaf(a2.y, d, acc[5]);
    acc[6] = fmaf(a3.x, d, acc[6]); acc[7] = fmaf(a3.y, d, acc[7]);
}

// ---------------- agg1: block-based, source-segment-phased ----------------
// 64 rows/block; quarter-wave (16 lanes) owns 4 rows, covers full 128-half row.
__global__ __launch_bounds__(256) void k_agg1(const __half* __restrict__ h1h,
                                              const float* __restrict__ dinv,
                                              const int* __restrict__ sbeg,
                                              const int* __restrict__ scnt,
                                              const unsigned short* __restrict__ esrc_seg,
                                              const float* __restrict__ b1,
                                              const float* __restrict__ mask,
                                              __half* __restrict__ h1p) {
    int t = threadIdx.x;
    int qw = t >> 4, ln = t & 15;
    int nbase = blockIdx.x * 64;
    const uint4* hv4 = (const uint4*)h1h;
    __half2 hacc[4][4];
    __half2 hz = __half2half2(__float2half(0.0f));
    #pragma unroll
    for (int k = 0; k < 4; k++) {
        hacc[k][0] = hz; hacc[k][1] = hz; hacc[k][2] = hz; hacc[k][3] = hz;
    }
    for (int s = 0; s < SEGN; s++) {
        #pragma unroll
        for (int k = 0; k < 4; k++) {
            int node = nbase + qw * 4 + k;
            if (node >= N_NODES) continue;
            int beg = sbeg[node * 4 + s];
            int cn = scnt[node * 4 + s];
            for (int e0 = 0; e0 < cn; e0 += 16) {
                int idx = e0 + ln;
                int sv = (idx < cn) ? (int)esrc_seg[beg + idx] : 0;
                float dv = (idx < cn) ? dinv[sv] : 0.0f;
                int n4 = min(16, cn - e0);
                n4 = (n4 + 3) & ~3;
                for (int j = 0; j < n4; j += 4) {
                    int base = qw * 16 + j;
                    int sA = __shfl(sv, base + 0); float dA = __shfl(dv, base + 0);
                    int sB = __shfl(sv, base + 1); float dB = __shfl(dv, base + 1);
                    int sC = __shfl(sv, base + 2); float dC = __shfl(dv, base + 2);
                    int sD = __shfl(sv, base + 3); float dD = __shfl(dv, base + 3);
                    uint4 vA = hv4[(size_t)sA * 16 + ln];
                    uint4 vB = hv4[(size_t)sB * 16 + ln];
                    uint4 vC = hv4[(size_t)sC * 16 + ln];
                    uint4 vD = hv4[(size_t)sD * 16 + ln];
                    __half2 hA = __half2half2(__float2half(dA));
                    __half2 hB = __half2half2(__float2half(dB));
                    __half2 hC = __half2half2(__float2half(dC));
                    __half2 hD = __half2half2(__float2half(dD));
                    hacc[k][0] = __hfma2(__builtin_bit_cast(__half2, vA.x), hA, hacc[k][0]);
                    hacc[k][1] = __hfma2(__builtin_bit_cast(__half2, vA.y), hA, hacc[k][1]);
                    hacc[k][2] = __hfma2(__builtin_bit_cast(__half2, vA.z), hA, hacc[k][2]);
                    hacc[k][3] = __hfma2(__builtin_bit_cast(__half2, vA.w), hA, hacc[k][3]);
                    hacc[k][0] = __hfma2(__builtin_bit_cast(__half2, vB.x), hB, hacc[k][0]);
                    hacc[k][1] = __hfma2(__builtin_bit_cast(__half2, vB.y), hB, hacc[k][1]);
                    hacc[k][2] = __hfma2(__builtin_bit_cast(__half2, vB.z), hB, hacc[k][2]);
                    hacc[k][3] = __hfma2(__builtin_bit_cast(__half2, vB.w), hB, hacc[k][3]);
                    hacc[k][0] = __hfma2(__builtin_bit_cast(__half2, vC.x), hC, hacc[k][0]);
                    hacc[k][1] = __hfma2(__builtin_bit_cast(__half2, vC.y), hC, hacc[k][1]);
                    hacc[k][2] = __hfma2(__builtin_bit_cast(__half2, vC.z), hC, hacc[k][2]);
                    hacc[k][3] = __hfma2(__builtin_bit_cast(__half2, vC.w), hC, hacc[k][3]);
                    hacc[k][0] = __hfma2(__builtin_bit_cast(__half2, vD.x), hD, hacc[k][0]);
                    hacc[k][1] = __hfma2(__builtin_bit_cast(__half2, vD.y), hD, hacc[k][1]);
                    hacc[k][2] = __hfma2(__builtin_bit_cast(__half2, vD.z), hD, hacc[k][2]);
                    hacc[k][3] = __hfma2(__builtin_bit_cast(__half2, vD.w), hD, hacc[k][3]);
                }
            }
        }
    }
    // epilogue: no cross-lane reduction needed (quarter-wave owns full rows)
    #pragma unroll
    for (int k = 0; k < 4; k++) {
        int node = nbase + qw * 4 + k;
        if (node >= N_NODES) continue;
        float di = dinv[node];
        float acc[8];
        #pragma unroll
        for (int k2 = 0; k2 < 4; k2++) {
            float2 f = __half22float2(hacc[k][k2]);
            acc[2 * k2] = f.x; acc[2 * k2 + 1] = f.y;
        }
        uint4 sv4 = hv4[(size_t)node * 16 + ln];
        acc8f(acc, sv4, di);
        float4 bb0 = ((const float4*)b1)[ln * 2];
        float4 bb1 = ((const float4*)b1)[ln * 2 + 1];
        const float4* mrow = (const float4*)(mask + (size_t)node * NHID);
        float4 mm0 = mrow[ln * 2];
        float4 mm1 = mrow[ln * 2 + 1];
        float o0 = fmaxf(fmaf(acc[0], di, bb0.x), 0.f) * mm0.x;
        float o1 = fmaxf(fmaf(acc[1], di, bb0.y), 0.f) * mm0.y;
        float o2 = fmaxf(fmaf(acc[2], di, bb0.z), 0.f) * mm0.z;
        float o3 = fmaxf(fmaf(acc[3], di, bb0.w), 0.f) * mm0.w;
        float o4 = fmaxf(fmaf(acc[4], di, bb1.x), 0.f) * mm1.x;
        float o5 = fmaxf(fmaf(acc[5], di, bb1.y), 0.f) * mm1.y;
        float o6 = fmaxf(fmaf(acc[6], di, bb1.z), 0.f) * mm1.z;
        float o7 = fmaxf(fmaf(acc[7], di, bb1.w), 0.f) * mm1.w;
        __half2 p0 = __float22half2_rn(make_float2(o0, o1));
        __half2 p1 = __float22half2_rn(make_float2(o2, o3));
        __half2 p2 = __float22half2_rn(make_float2(o4, o5));
        __half2 p3 = __float22half2_rn(make_float2(o6, o7));
        uint4 st;
        st.x = __builtin_bit_cast(unsigned int, p0);
        st.y = __builtin_bit_cast(unsigned int, p1);
        st.z = __builtin_bit_cast(unsigned int, p2);
        st.w = __builtin_bit_cast(unsigned int, p3);
        ((uint4*)h1p)[(size_t)node * 16 + ln] = st;
    }
}

// ---------------- agg2 + bias + log_softmax (stride-64 rows, fp16 accum) -------
__global__ __launch_bounds__(64) void k_agg2(const __half* __restrict__ h2p,
                                             const float* __restrict__ dinv,
                                             const int* __restrict__ row_beg,
                                             const int* __restrict__ row_cnt,
                                             const unsigned short* __restrict__ esrc,
                                             const float* __restrict__ b2,
                                             float* __restrict__ out) {
    int i = blockIdx.x;
    int lane = threadIdx.x;
    int o8 = lane >> 3;
    int fl = lane & 7;
    const uint4* hv4 = (const uint4*)h2p;   // row stride 8 uint4 (128B aligned)
    float di = dinv[i];
    __half2 hacc[4];
    __half2 hz = __half2half2(__float2half(0.0f));
    hacc[0] = hz; hacc[1] = hz; hacc[2] = hz; hacc[3] = hz;
    int s0 = row_beg[i], cnt = row_cnt[i];
    for (int base = 0; base < cnt; base += 64) {
        int idx = base + lane;
        int sv = (idx < cnt) ? (int)esrc[s0 + idx] : 0;
        float dv = (idx < cnt) ? dinv[sv] : 0.0f;
        int n = min(64, cnt - base);
        int nr = (n + 31) & ~31;
        for (int j = 0; j < nr; j += 32) {
            int ss[4]; __half2 dd[4]; uint4 vv[4];
            #pragma unroll
            for (int k = 0; k < 4; k++) {
                int jx = j + 8 * k + o8;
                ss[k] = __shfl(sv, jx);
                float df = __shfl(dv, jx);
                dd[k] = __half2half2(__float2half(df));
            }
            #pragma unroll
            for (int k = 0; k < 4; k++) vv[k] = hv4[(size_t)ss[k] * 8 + fl];
            #pragma unroll
            for (int k = 0; k < 4; k++) {
                hacc[0] = __hfma2(__builtin_bit_cast(__half2, vv[k].x), dd[k], hacc[0]);
                hacc[1] = __hfma2(__builtin_bit_cast(__half2, vv[k].y), dd[k], hacc[1]);
                hacc[2] = __hfma2(__builtin_bit_cast(__half2, vv[k].z), dd[k], hacc[2]);
                hacc[3] = __hfma2(__builtin_bit_cast(__half2, vv[k].w), dd[k], hacc[3]);
            }
        }
    }
    float acc[8];
    #pragma unroll
    for (int k2 = 0; k2 < 4; k2++) {
        float2 f = __half22float2(hacc[k2]);
        acc[2 * k2] = f.x; acc[2 * k2 + 1] = f.y;
    }
    if (o8 == 0) {
        uint4 sv4 = hv4[(size_t)i * 8 + fl];
        acc8f(acc, sv4, di);
    }
    #pragma unroll
    for (int k = 0; k < 8; k++) {
        acc[k] += __shfl_xor(acc[k], 8);
        acc[k] += __shfl_xor(acc[k], 16);
        acc[k] += __shfl_xor(acc[k], 32);
    }
    if (o8 == 0) {
        bool act = (fl < 5);
        float val[8];
        float m = -INFINITY;
        if (act) {
            float4 bb0 = ((const float4*)b2)[fl * 2];
            float4 bb1 = ((const float4*)b2)[fl * 2 + 1];
            val[0] = fmaf(acc[0], di, bb0.x);
            val[1] = fmaf(acc[1], di, bb0.y);
            val[2] = fmaf(acc[2], di, bb0.z);
            val[3] = fmaf(acc[3], di, bb0.w);
            val[4] = fmaf(acc[4], di, bb1.x);
            val[5] = fmaf(acc[5], di, bb1.y);
            val[6] = fmaf(acc[6], di, bb1.z);
            val[7] = fmaf(acc[7], di, bb1.w);
            #pragma unroll
            for (int k = 0; k < 8; k++) m = fmaxf(m, val[k]);
        }
        m = fmaxf(m, __shfl_xor(m, 1));
        m = fmaxf(m, __shfl_xor(m, 2));
        m = fmaxf(m, __shfl_xor(m, 4));
        float ss = 0.f;
        if (act) {
            #pragma unroll
            for (int k = 0; k < 8; k++) ss += expf(val[k] - m);
        }
        ss += __shfl_xor(ss, 1);
        ss += __shfl_xor(ss, 2);
        ss += __shfl_xor(ss, 4);
        if (act) {
            float ls = m + logf(ss);
            float4 r0 = make_float4(val[0] - ls, val[1] - ls, val[2] - ls, val[3] - ls);
            float4 r1 = make_float4(val[4] - ls, val[5] - ls, val[6] - ls, val[7] - ls);
            float4* orow = (float4*)(out + (size_t)i * NCLASS + fl * 8);
            orow[0] = r0;
            orow[1] = r1;
        }
    }
}

extern "C" void kernel_launch(void* const* d_in, const int* in_sizes, int n_in,
                              void* d_out, int out_size, void* d_ws, size_t ws_size,
                              hipStream_t stream) {
    const float* x    = (const float*)d_in[0];
    const int*   ei   = (const int*)d_in[1];
    const float* W1   = (const float*)d_in[2];
    const float* b1   = (const float*)d_in[3];
    const float* W2   = (const float*)d_in[4];
    const float* b2   = (const float*)d_in[5];
    const float* mask = (const float*)d_in[6];
    float* out = (float*)d_out;

    const int* src = ei;
    const int* dst = ei + N_EDGES;

    char* ws = (char*)d_ws;
    size_t off = 0;
    __half* h1p    = (__half*)(ws + off); off += (size_t)N_NODES * NHID * 2;   // 12.8 MB
    __half* h1h    = (__half*)(ws + off); off += (size_t)N_NODES * NHID * 2;   // 12.8 MB
    unsigned short* esrc_seg = (unsigned short*)(ws + off);
    off += ((size_t)NBUCK * CAP * 2 + 255) & ~(size_t)255;                     // 4.0 MB
    unsigned short* esrc_row = (unsigned short*)(ws + off);
    off += ((size_t)NBUCK * CAP * 2 + 255) & ~(size_t)255;                     // 4.0 MB
    int*   sbeg    = (int*)   (ws + off); off += (size_t)N_NODES * 4 * 4;      // 800 KB
    int*   scnt    = (int*)   (ws + off); off += (size_t)N_NODES * 4 * 4;      // 800 KB
    float* dinv    = (float*) (ws + off); off += 200192;
    int*   row_beg = (int*)   (ws + off); off += 200192;
    int*   row_cnt = (int*)   (ws + off); off += 200192;
    int*   gcur    = (int*)   (ws + off); off += 4096;
    __half* w1t    = (__half*)(ws + off); off += 128 * 256 * 2;                // 64 KB
    __half* w2t    = (__half*)(ws + off); off += 48 * 128 * 2;                 // 12 KB

    unsigned int* packed = (unsigned int*)h1p;  // binA/binB lifetime only (8 MB)
    __half* h2p = h1h;                           // gemm2/agg2 lifetime only (6.4 MB)

    k_prep<<<128, 256, 0, stream>>>(W1, W2, w1t, w2t, gcur);
    k_binA<<<(N_EDGES + EPB - 1) / EPB, 256, 0, stream>>>(src, dst, gcur, packed);
    k_binB<<<NBUCK, 256, 0, stream>>>(gcur, packed, esrc_seg, esrc_row,
                                      sbeg, scnt, row_beg, row_cnt, dinv);

    k_gemm1<<<(N_NODES + 63) / 64, 256, 0, stream>>>(x, w1t, h1h);
    k_agg1<<<(N_NODES + 63) / 64, 256, 0, stream>>>(h1h, dinv, sbeg, scnt,
                                                    esrc_seg, b1, mask, h1p);
    k_gemm2<<<(N_NODES + 63) / 64, 256, 0, stream>>>(h1p, w2t, h2p);
    k_agg2<<<N_NODES, 64, 0, stream>>>(h2p, dinv, row_beg, row_cnt, esrc_row, b2, out);
}

// Round 11
// 271.290 us; speedup vs baseline: 1.0430x; 1.0271x over previous
//
#include <hip/hip_runtime.h>
#include <hip/hip_fp16.h>
#include <math.h>

#define N_NODES 50000
#define N_EDGES 1600000
#define NFEAT 256
#define NHID 128
#define NCLASS 40

#define BSHIFT 7
#define NBUCK 391            // ceil(50000 / 128)
#define CAP 5120             // per-bucket capacity (mean 4092)
#define EPB 4096             // edges per binA block -> 391 binA blocks
#define SEGN 4
#define SEGSZ 12800          // src segment: 12800 rows * 256B = 3.2MB of h1h
#define NG1 782              // gemm1 blocks in fused launch

typedef _Float16 f16x8 __attribute__((ext_vector_type(8)));
typedef float f32x4 __attribute__((ext_vector_type(4)));

// ---------------- prep: W transposes to fp16 + gcur zeroing ----------------
__global__ __launch_bounds__(256) void k_prep(const float* __restrict__ W1,
                                              const float* __restrict__ W2,
                                              __half* __restrict__ w1t,
                                              __half* __restrict__ w2t,
                                              int* __restrict__ gcur) {
    int t = blockIdx.x * 256 + threadIdx.x;
    if (t < NBUCK) gcur[t] = 0;
    if (t < 128 * 256) {
        int n = t >> 8, k = t & 255;
        w1t[t] = __float2half(W1[k * NHID + n]);
    }
    if (t < 48 * 128) {
        int n = t >> 7, k = t & 127;
        w2t[t] = __float2half(n < NCLASS ? W2[k * NCLASS + n] : 0.0f);
    }
}

// ---------------- fused: binA (coarse binning) + GEMM1 (MFMA) ----------------
#define G1_LDA 72
#define G1_LDB 72
#define G1_LDE 136
__global__ __launch_bounds__(256) void k_binA_gemm1(
        const int* __restrict__ src, const int* __restrict__ dst,
        int* __restrict__ gcur, unsigned int* __restrict__ packed,
        const float* __restrict__ x, const __half* __restrict__ w1t,
        __half* __restrict__ h1h) {
    __shared__ __half smem[64 * G1_LDA + 128 * G1_LDB];   // 27.6 KB
    int t = threadIdx.x;
    if (blockIdx.x >= NG1) {
        // ---------- binA ----------
        int bid = blockIdx.x - NG1;
        int* lhist = (int*)smem;
        int* lbase = lhist + NBUCK;
        int* lcur  = lbase + NBUCK;
        for (int i = t; i < NBUCK; i += 256) { lhist[i] = 0; lcur[i] = 0; }
        __syncthreads();
        int e0 = bid * EPB;
        int e1 = min(e0 + EPB, N_EDGES);
        for (int e = e0 + t; e < e1; e += 256) {
            int b = dst[e] >> BSHIFT;
            atomicAdd(&lhist[b], 1);
        }
        __syncthreads();
        for (int i = t; i < NBUCK; i += 256)
            lbase[i] = atomicAdd(&gcur[i], lhist[i]);
        __syncthreads();
        for (int e = e0 + t; e < e1; e += 256) {
            int d = dst[e];
            int b = d >> BSHIFT;
            int r = atomicAdd(&lcur[b], 1);
            int pos = lbase[b] + r;
            if (pos < CAP)
                packed[(size_t)b * CAP + pos] =
                    ((unsigned int)src[e] << BSHIFT) | (unsigned int)(d & 127);
        }
        return;
    }
    // ---------- gemm1 ----------
    __half* sA = smem;
    __half* sB = smem + 64 * G1_LDA;
    int rbase = blockIdx.x * 64;
    int lane = t & 63, wv = t >> 6;
    int m = lane & 15, quad = lane >> 4;
    f32x4 acc[8];
    #pragma unroll
    for (int i = 0; i < 8; i++) acc[i] = (f32x4)0.0f;

    int arow = t >> 2, aseg = t & 3;
    int grow = rbase + arow;
    bool avalid = grow < N_NODES;
    int bn = t >> 1, bseg = t & 1;

    for (int k0 = 0; k0 < NFEAT; k0 += 64) {
        const float4* gs = (const float4*)(x + (size_t)grow * NFEAT + k0 + aseg * 16);
        __half* ad = sA + arow * G1_LDA + aseg * 16;
        #pragma unroll
        for (int i = 0; i < 4; i++) {
            float4 v = avalid ? gs[i] : make_float4(0.f, 0.f, 0.f, 0.f);
            __half2 h0 = __float22half2_rn(make_float2(v.x, v.y));
            __half2 h1 = __float22half2_rn(make_float2(v.z, v.w));
            uint2 st;
            st.x = __builtin_bit_cast(unsigned int, h0);
            st.y = __builtin_bit_cast(unsigned int, h1);
            *(uint2*)(ad + i * 4) = st;
        }
        const uint4* ws4 = (const uint4*)(w1t + bn * NFEAT + k0 + bseg * 32);
        uint4* bd = (uint4*)(sB + bn * G1_LDB + bseg * 32);
        #pragma unroll
        for (int i = 0; i < 4; i++) bd[i] = ws4[i];
        __syncthreads();
        #pragma unroll
        for (int kk = 0; kk < 64; kk += 32) {
            f16x8 af = *(const f16x8*)(sA + (wv * 16 + m) * G1_LDA + kk + quad * 8);
            #pragma unroll
            for (int t8 = 0; t8 < 8; t8++) {
                f16x8 bf = *(const f16x8*)(sB + (t8 * 16 + m) * G1_LDB + kk + quad * 8);
                acc[t8] = __builtin_amdgcn_mfma_f32_16x16x32_f16(af, bf, acc[t8], 0, 0, 0);
            }
        }
        __syncthreads();
    }
    __half* eb = smem;
    #pragma unroll
    for (int t8 = 0; t8 < 8; t8++) {
        #pragma unroll
        for (int r = 0; r < 4; r++)
            eb[(wv * 16 + quad * 4 + r) * G1_LDE + t8 * 16 + m] = __float2half(acc[t8][r]);
    }
    __syncthreads();
    if (avalid) {
        const uint4* es = (const uint4*)(eb + arow * G1_LDE + aseg * 32);
        uint4* od = (uint4*)(h1h + (size_t)grow * NHID + aseg * 32);
        #pragma unroll
        for (int i = 0; i < 4; i++) od[i] = es[i];
    }
}

// ---------------- pass B: dual in-LDS sorts per bucket ----------------
__global__ __launch_bounds__(256) void k_binB(const int* __restrict__ gcur,
                                              const unsigned int* __restrict__ packed,
                                              unsigned short* __restrict__ esrc_seg,
                                              unsigned short* __restrict__ esrc_row,
                                              int* __restrict__ sbeg,
                                              int* __restrict__ scnt,
                                              int* __restrict__ row_beg,
                                              int* __restrict__ row_cnt,
                                              float* __restrict__ dinv) {
    __shared__ unsigned int sp[CAP];     // 20 KB
    __shared__ int hist[512];
    __shared__ int scan[512];
    __shared__ int cur[512];
    __shared__ int psum[64];
    int b = blockIdx.x;
    int t = threadIdx.x;
    int cnt = min(gcur[b], CAP);
    for (int i = t; i < 512; i += 256) { hist[i] = 0; cur[i] = 0; }
    __syncthreads();
    const unsigned int* pin = packed + (size_t)b * CAP;
    for (int i = t; i < cnt; i += 256) {
        unsigned int w = pin[i];
        sp[i] = w;
        int srcv = (int)(w >> BSHIFT);
        atomicAdd(&hist[(srcv / SEGSZ) * 128 + (int)(w & 127u)], 1);
    }
    __syncthreads();
    if (t < 64) {
        int s = 0;
        #pragma unroll
        for (int j = 0; j < 8; j++) s += hist[t * 8 + j];
        psum[t] = s;
    }
    __syncthreads();
    if (t == 0) {
        int s = 0;
        for (int j = 0; j < 64; j++) { int v = psum[j]; psum[j] = s; s += v; }
    }
    __syncthreads();
    if (t < 64) {
        int s = psum[t];
        #pragma unroll
        for (int j = 0; j < 8; j++) { scan[t * 8 + j] = s; s += hist[t * 8 + j]; }
    }
    __syncthreads();
    for (int i = t; i < cnt; i += 256) {
        unsigned int w = sp[i];
        int srcv = (int)(w >> BSHIFT);
        int key = (srcv / SEGSZ) * 128 + (int)(w & 127u);
        int r = atomicAdd(&cur[key], 1);
        esrc_seg[(size_t)b * CAP + scan[key] + r] = (unsigned short)srcv;
    }
    if (t < 128) {
        int node = b * 128 + t;
        if (node < N_NODES) {
            int tot = 0;
            #pragma unroll
            for (int s = 0; s < SEGN; s++) {
                sbeg[node * 4 + s] = b * CAP + scan[s * 128 + t];
                scnt[node * 4 + s] = hist[s * 128 + t];
                tot += hist[s * 128 + t];
            }
            row_cnt[node] = tot;
            dinv[node] = rsqrtf((float)(tot + 1));
        }
    }
    __syncthreads();
    if (t < 128) { hist[t] = 0; cur[t] = 0; }
    __syncthreads();
    for (int i = t; i < cnt; i += 256) atomicAdd(&hist[sp[i] & 127u], 1);
    __syncthreads();
    if (t == 0) {
        int s = 0;
        for (int j = 0; j < 128; j++) { int v = hist[j]; scan[j] = s; s += v; }
    }
    __syncthreads();
    for (int i = t; i < cnt; i += 256) {
        unsigned int w = sp[i];
        int dl = (int)(w & 127u);
        int r = atomicAdd(&cur[dl], 1);
        esrc_row[(size_t)b * CAP + scan[dl] + r] = (unsigned short)(w >> BSHIFT);
    }
    if (t < 128) {
        int node = b * 128 + t;
        if (node < N_NODES) row_beg[node] = b * CAP + scan[t];
    }
}

// ---------------- GEMM2 (MFMA): h2p(fp16, stride 64) = h1p @ W2 ----------------
#define G2_LDA 136
#define G2_LDB 136
#define G2_LDE 72
__global__ __launch_bounds__(256) void k_gemm2(const __half* __restrict__ h1p,
                                               const __half* __restrict__ w2t,
                                               __half* __restrict__ h2p) {
    __shared__ __half smem[64 * G2_LDA + 48 * G2_LDB];  // 30.5 KB
    __half* sA = smem;
    __half* sB = smem + 64 * G2_LDA;
    int t = threadIdx.x;
    int rbase = blockIdx.x * 64;
    int lane = t & 63, wv = t >> 6;
    int m = lane & 15, quad = lane >> 4;
    f32x4 acc[3];
    #pragma unroll
    for (int i = 0; i < 3; i++) acc[i] = (f32x4)0.0f;

    int arow = t >> 2, aseg = t & 3;
    int grow = rbase + arow;
    bool avalid = grow < N_NODES;

    #pragma unroll
    for (int i = 0; i < 3; i++) {
        int idx = t + i * 256;
        int n = idx >> 4, seg = idx & 15;
        *(uint4*)(sB + n * G2_LDB + seg * 8) = *(const uint4*)(w2t + n * NHID + seg * 8);
    }
    {
        const uint4* gs = (const uint4*)(h1p + (size_t)grow * NHID + aseg * 32);
        uint4* ad = (uint4*)(sA + arow * G2_LDA + aseg * 32);
        uint4 z; z.x = z.y = z.z = z.w = 0;
        #pragma unroll
        for (int i = 0; i < 4; i++) ad[i] = avalid ? gs[i] : z;
    }
    __syncthreads();
    #pragma unroll
    for (int kk = 0; kk < 128; kk += 32) {
        f16x8 af = *(const f16x8*)(sA + (wv * 16 + m) * G2_LDA + kk + quad * 8);
        #pragma unroll
        for (int t3 = 0; t3 < 3; t3++) {
            f16x8 bf = *(const f16x8*)(sB + (t3 * 16 + m) * G2_LDB + kk + quad * 8);
            acc[t3] = __builtin_amdgcn_mfma_f32_16x16x32_f16(af, bf, acc[t3], 0, 0, 0);
        }
    }
    __syncthreads();
    __half* eb = smem;
    #pragma unroll
    for (int t3 = 0; t3 < 3; t3++) {
        #pragma unroll
        for (int r = 0; r < 4; r++)
            eb[(wv * 16 + quad * 4 + r) * G2_LDE + t3 * 16 + m] = __float2half(acc[t3][r]);
    }
    {
        int zr = t >> 2, zc = 48 + (t & 3) * 4;
        uint2 z; z.x = z.y = 0;
        *(uint2*)(eb + zr * G2_LDE + zc) = z;
    }
    __syncthreads();
    #pragma unroll
    for (int i = 0; i < 2; i++) {
        int idx = t + i * 256;
        int row = idx >> 3, seg = idx & 7;
        int gr = rbase + row;
        if (gr < N_NODES)
            *(uint4*)(h2p + (size_t)gr * 64 + seg * 8) = *(const uint4*)(eb + row * G2_LDE + seg * 8);
    }
}

__device__ __forceinline__ void acc8f(float* acc, uint4 v, float d) {
    float2 a0 = __half22float2(__builtin_bit_cast(__half2, v.x));
    float2 a1 = __half22float2(__builtin_bit_cast(__half2, v.y));
    float2 a2 = __half22float2(__builtin_bit_cast(__half2, v.z));
    float2 a3 = __half22float2(__builtin_bit_cast(__half2, v.w));
    acc[0] = fmaf(a0.x, d, acc[0]); acc[1] = fmaf(a0.y, d, acc[1]);
    acc[2] = fmaf(a1.x, d, acc[2]); acc[3] = fmaf(a1.y, d, acc[3]);
    acc[4] = fmaf(a2.x, d, acc[4]); acc[5] = fmaf(a2.y, d, acc[5]);
    acc[6] = fmaf(a3.x, d, acc[6]); acc[7] = fmaf(a3.y, d, acc[7]);
}

// ---------------- agg1: segment-phased, 32 nodes/block, 8-deep MLP ----------
// quarter-wave (16 lanes) owns 2 nodes; 8 gathers in flight per inner step.
__global__ __launch_bounds__(256) void k_agg1(const __half* __restrict__ h1h,
                                              const float* __restrict__ dinv,
                                              const int* __restrict__ sbeg,
                                              const int* __restrict__ scnt,
                                              const unsigned short* __restrict__ esrc_seg,
                                              const float* __restrict__ b1,
                                              const float* __restrict__ mask,
                                              __half* __restrict__ h1p) {
    int t = threadIdx.x;
    int qw = t >> 4, ln = t & 15;     // qw*16 wraps mod 64 in __shfl -> wave-local quarter
    int nbase = blockIdx.x * 32;
    const uint4* hv4 = (const uint4*)h1h;
    __half2 hacc[2][4];
    __half2 hz = __half2half2(__float2half(0.0f));
    #pragma unroll
    for (int k = 0; k < 2; k++) {
        hacc[k][0] = hz; hacc[k][1] = hz; hacc[k][2] = hz; hacc[k][3] = hz;
    }
    for (int s = 0; s < SEGN; s++) {
        #pragma unroll
        for (int k = 0; k < 2; k++) {
            int node = nbase + qw * 2 + k;
            if (node >= N_NODES) continue;
            int beg = sbeg[node * 4 + s];
            int cn = scnt[node * 4 + s];
            for (int e0 = 0; e0 < cn; e0 += 16) {
                int idx = e0 + ln;
                int sv = (idx < cn) ? (int)esrc_seg[beg + idx] : 0;
                float dv = (idx < cn) ? dinv[sv] : 0.0f;
                int n4 = min(16, cn - e0);
                int n8 = (n4 + 7) & ~7;
                for (int j = 0; j < n8; j += 8) {
                    int ss[8]; float dd[8]; uint4 vv[8];
                    #pragma unroll
                    for (int u = 0; u < 8; u++) {
                        ss[u] = __shfl(sv, qw * 16 + j + u);
                        dd[u] = __shfl(dv, qw * 16 + j + u);
                    }
                    #pragma unroll
                    for (int u = 0; u < 8; u++) vv[u] = hv4[(size_t)ss[u] * 16 + ln];
                    #pragma unroll
                    for (int u = 0; u < 8; u++) {
                        __half2 h = __half2half2(__float2half(dd[u]));
                        hacc[k][0] = __hfma2(__builtin_bit_cast(__half2, vv[u].x), h, hacc[k][0]);
                        hacc[k][1] = __hfma2(__builtin_bit_cast(__half2, vv[u].y), h, hacc[k][1]);
                        hacc[k][2] = __hfma2(__builtin_bit_cast(__half2, vv[u].z), h, hacc[k][2]);
                        hacc[k][3] = __hfma2(__builtin_bit_cast(__half2, vv[u].w), h, hacc[k][3]);
                    }
                }
            }
        }
    }
    #pragma unroll
    for (int k = 0; k < 2; k++) {
        int node = nbase + qw * 2 + k;
        if (node >= N_NODES) continue;
        float di = dinv[node];
        float acc[8];
        #pragma unroll
        for (int k2 = 0; k2 < 4; k2++) {
            float2 f = __half22float2(hacc[k][k2]);
            acc[2 * k2] = f.x; acc[2 * k2 + 1] = f.y;
        }
        uint4 sv4 = hv4[(size_t)node * 16 + ln];
        acc8f(acc, sv4, di);
        float4 bb0 = ((const float4*)b1)[ln * 2];
        float4 bb1 = ((const float4*)b1)[ln * 2 + 1];
        const float4* mrow = (const float4*)(mask + (size_t)node * NHID);
        float4 mm0 = mrow[ln * 2];
        float4 mm1 = mrow[ln * 2 + 1];
        float o0 = fmaxf(fmaf(acc[0], di, bb0.x), 0.f) * mm0.x;
        float o1 = fmaxf(fmaf(acc[1], di, bb0.y), 0.f) * mm0.y;
        float o2 = fmaxf(fmaf(acc[2], di, bb0.z), 0.f) * mm0.z;
        float o3 = fmaxf(fmaf(acc[3], di, bb0.w), 0.f) * mm0.w;
        float o4 = fmaxf(fmaf(acc[4], di, bb1.x), 0.f) * mm1.x;
        float o5 = fmaxf(fmaf(acc[5], di, bb1.y), 0.f) * mm1.y;
        float o6 = fmaxf(fmaf(acc[6], di, bb1.z), 0.f) * mm1.z;
        float o7 = fmaxf(fmaf(acc[7], di, bb1.w), 0.f) * mm1.w;
        __half2 p0 = __float22half2_rn(make_float2(o0, o1));
        __half2 p1 = __float22half2_rn(make_float2(o2, o3));
        __half2 p2 = __float22half2_rn(make_float2(o4, o5));
        __half2 p3 = __float22half2_rn(make_float2(o6, o7));
        uint4 st;
        st.x = __builtin_bit_cast(unsigned int, p0);
        st.y = __builtin_bit_cast(unsigned int, p1);
        st.z = __builtin_bit_cast(unsigned int, p2);
        st.w = __builtin_bit_cast(unsigned int, p3);
        ((uint4*)h1p)[(size_t)node * 16 + ln] = st;
    }
}

// ---------------- agg2 + bias + log_softmax (stride-64 rows, fp16 accum) -------
__global__ __launch_bounds__(64) void k_agg2(const __half* __restrict__ h2p,
                                             const float* __restrict__ dinv,
                                             const int* __restrict__ row_beg,
                                             const int* __restrict__ row_cnt,
                                             const unsigned short* __restrict__ esrc,
                                             const float* __restrict__ b2,
                                             float* __restrict__ out) {
    int i = blockIdx.x;
    int lane = threadIdx.x;
    int o8 = lane >> 3;
    int fl = lane & 7;
    const uint4* hv4 = (const uint4*)h2p;
    float di = dinv[i];
    __half2 hacc[4];
    __half2 hz = __half2half2(__float2half(0.0f));
    hacc[0] = hz; hacc[1] = hz; hacc[2] = hz; hacc[3] = hz;
    int s0 = row_beg[i], cnt = row_cnt[i];
    for (int base = 0; base < cnt; base += 64) {
        int idx = base + lane;
        int sv = (idx < cnt) ? (int)esrc[s0 + idx] : 0;
        float dv = (idx < cnt) ? dinv[sv] : 0.0f;
        int n = min(64, cnt - base);
        int nr = (n + 31) & ~31;
        for (int j = 0; j < nr; j += 32) {
            int ss[4]; __half2 dd[4]; uint4 vv[4];
            #pragma unroll
            for (int k = 0; k < 4; k++) {
                int jx = j + 8 * k + o8;
                ss[k] = __shfl(sv, jx);
                float df = __shfl(dv, jx);
                dd[k] = __half2half2(__float2half(df));
            }
            #pragma unroll
            for (int k = 0; k < 4; k++) vv[k] = hv4[(size_t)ss[k] * 8 + fl];
            #pragma unroll
            for (int k = 0; k < 4; k++) {
                hacc[0] = __hfma2(__builtin_bit_cast(__half2, vv[k].x), dd[k], hacc[0]);
                hacc[1] = __hfma2(__builtin_bit_cast(__half2, vv[k].y), dd[k], hacc[1]);
                hacc[2] = __hfma2(__builtin_bit_cast(__half2, vv[k].z), dd[k], hacc[2]);
                hacc[3] = __hfma2(__builtin_bit_cast(__half2, vv[k].w), dd[k], hacc[3]);
            }
        }
    }
    float acc[8];
    #pragma unroll
    for (int k2 = 0; k2 < 4; k2++) {
        float2 f = __half22float2(hacc[k2]);
        acc[2 * k2] = f.x; acc[2 * k2 + 1] = f.y;
    }
    if (o8 == 0) {
        uint4 sv4 = hv4[(size_t)i * 8 + fl];
        acc8f(acc, sv4, di);
    }
    #pragma unroll
    for (int k = 0; k < 8; k++) {
        acc[k] += __shfl_xor(acc[k], 8);
        acc[k] += __shfl_xor(acc[k], 16);
        acc[k] += __shfl_xor(acc[k], 32);
    }
    if (o8 == 0) {
        bool act = (fl < 5);
        float val[8];
        float m = -INFINITY;
        if (act) {
            float4 bb0 = ((const float4*)b2)[fl * 2];
            float4 bb1 = ((const float4*)b2)[fl * 2 + 1];
            val[0] = fmaf(acc[0], di, bb0.x);
            val[1] = fmaf(acc[1], di, bb0.y);
            val[2] = fmaf(acc[2], di, bb0.z);
            val[3] = fmaf(acc[3], di, bb0.w);
            val[4] = fmaf(acc[4], di, bb1.x);
            val[5] = fmaf(acc[5], di, bb1.y);
            val[6] = fmaf(acc[6], di, bb1.z);
            val[7] = fmaf(acc[7], di, bb1.w);
            #pragma unroll
            for (int k = 0; k < 8; k++) m = fmaxf(m, val[k]);
        }
        m = fmaxf(m, __shfl_xor(m, 1));
        m = fmaxf(m, __shfl_xor(m, 2));
        m = fmaxf(m, __shfl_xor(m, 4));
        float ss = 0.f;
        if (act) {
            #pragma unroll
            for (int k = 0; k < 8; k++) ss += expf(val[k] - m);
        }
        ss += __shfl_xor(ss, 1);
        ss += __shfl_xor(ss, 2);
        ss += __shfl_xor(ss, 4);
        if (act) {
            float ls = m + logf(ss);
            float4 r0 = make_float4(val[0] - ls, val[1] - ls, val[2] - ls, val[3] - ls);
            float4 r1 = make_float4(val[4] - ls, val[5] - ls, val[6] - ls, val[7] - ls);
            float4* orow = (float4*)(out + (size_t)i * NCLASS + fl * 8);
            orow[0] = r0;
            orow[1] = r1;
        }
    }
}

extern "C" void kernel_launch(void* const* d_in, const int* in_sizes, int n_in,
                              void* d_out, int out_size, void* d_ws, size_t ws_size,
                              hipStream_t stream) {
    const float* x    = (const float*)d_in[0];
    const int*   ei   = (const int*)d_in[1];
    const float* W1   = (const float*)d_in[2];
    const float* b1   = (const float*)d_in[3];
    const float* W2   = (const float*)d_in[4];
    const float* b2   = (const float*)d_in[5];
    const float* mask = (const float*)d_in[6];
    float* out = (float*)d_out;

    const int* src = ei;
    const int* dst = ei + N_EDGES;

    char* ws = (char*)d_ws;
    size_t off = 0;
    __half* h1p    = (__half*)(ws + off); off += (size_t)N_NODES * NHID * 2;   // 12.8 MB
    __half* h1h    = (__half*)(ws + off); off += (size_t)N_NODES * NHID * 2;   // 12.8 MB
    unsigned short* esrc_seg = (unsigned short*)(ws + off);
    off += ((size_t)NBUCK * CAP * 2 + 255) & ~(size_t)255;                     // 4.0 MB
    unsigned short* esrc_row = (unsigned short*)(ws + off);
    off += ((size_t)NBUCK * CAP * 2 + 255) & ~(size_t)255;                     // 4.0 MB
    int*   sbeg    = (int*)   (ws + off); off += (size_t)N_NODES * 4 * 4;      // 800 KB
    int*   scnt    = (int*)   (ws + off); off += (size_t)N_NODES * 4 * 4;      // 800 KB
    float* dinv    = (float*) (ws + off); off += 200192;
    int*   row_beg = (int*)   (ws + off); off += 200192;
    int*   row_cnt = (int*)   (ws + off); off += 200192;
    int*   gcur    = (int*)   (ws + off); off += 4096;
    __half* w1t    = (__half*)(ws + off); off += 128 * 256 * 2;                // 64 KB
    __half* w2t    = (__half*)(ws + off); off += 48 * 128 * 2;                 // 12 KB

    unsigned int* packed = (unsigned int*)h1p;  // binA/binB lifetime only (8 MB)
    __half* h2p = h1h;                           // gemm2/agg2 lifetime only (6.4 MB)

    k_prep<<<128, 256, 0, stream>>>(W1, W2, w1t, w2t, gcur);
    k_binA_gemm1<<<NG1 + (N_EDGES + EPB - 1) / EPB, 256, 0, stream>>>(
        src, dst, gcur, packed, x, w1t, h1h);
    k_binB<<<NBUCK, 256, 0, stream>>>(gcur, packed, esrc_seg, esrc_row,
                                      sbeg, scnt, row_beg, row_cnt, dinv);

    k_agg1<<<(N_NODES + 31) / 32, 256, 0, stream>>>(h1h, dinv, sbeg, scnt,
                                                    esrc_seg, b1, mask, h1p);
    k_gemm2<<<(N_NODES + 63) / 64, 256, 0, stream>>>(h1p, w2t, h2p);
    k_agg2<<<N_NODES, 64, 0, stream>>>(h2p, dinv, row_beg, row_cnt, esrc_row, b2, out);
}